// Round 5
// baseline (203.665 us; speedup 1.0000x reference)
//
#include <hip/hip_runtime.h>
#include <math.h>

#define NV 720
#define NU 736
#define NXY 512

// ---------------- Stage 1+2: cosine weight + Ram-Lak Toeplitz GEMM (+ trig table) ------
__global__ __launch_bounds__(192) void filter_kernel(const float* __restrict__ sino,
                                                     float* __restrict__ Q,
                                                     float4* __restrict__ trig) {
    __shared__ float s4[2][368][4];   // [parity][m][view]
    __shared__ float wco[736];        // wco[i] = -1/(pi*(2i-735)*DU)^2
    const int v0 = blockIdx.x * 4;
    const int t = threadIdx.x;

    if (t < 4) {
        int v = v0 + t;
        float beta = (float)((double)v * (2.0 * M_PI / 720.0));
        float cb = cosf(beta), sb = sinf(beta);
        const float K = (float)(1085.6 / 1.2858);   // DSD/DU
        trig[v] = make_float4(cb * K, sb * K, cb, sb);
    }
    for (int i = t; i < 736; i += 192) {
        double n = (double)(2 * i - 735);
        double a = M_PI * n * 1.2858;
        wco[i] = (float)(-1.0 / (a * a));
    }
    const float DSD2 = (float)(1085.6 * 1085.6);
    for (int vv = 0; vv < 4; ++vv) {
        for (int u = t; u < 736; u += 192) {
            float us = ((float)u - 367.5f) * 1.2858f;
            float cw = 1085.6f / sqrtf(DSD2 + us * us);
            s4[u & 1][u >> 1][vv] = sino[(v0 + vv) * NU + u] * cw;
        }
    }
    __syncthreads();

    if (t < 184) {
        const int pj = (t < 92) ? 1 : 0;
        const int J0 = (t < 92) ? t : t - 92;
        const int q = 1 - pj;
        float acc[4][4];
        #pragma unroll
        for (int r = 0; r < 4; ++r)
            #pragma unroll
            for (int vv = 0; vv < 4; ++vv) acc[r][vv] = 0.0f;

        const int ibase0 = J0 + 367 + pj;
        #pragma unroll 4
        for (int m = 0; m < 368; ++m) {
            const float4 sv = *(const float4*)&s4[q][m][0];
            const int ib = ibase0 - m;
            const float w0 = wco[ib];
            const float w1 = wco[ib + 92];
            const float w2 = wco[ib + 184];
            const float w3 = wco[ib + 276];
            acc[0][0] = fmaf(w0, sv.x, acc[0][0]);
            acc[0][1] = fmaf(w0, sv.y, acc[0][1]);
            acc[0][2] = fmaf(w0, sv.z, acc[0][2]);
            acc[0][3] = fmaf(w0, sv.w, acc[0][3]);
            acc[1][0] = fmaf(w1, sv.x, acc[1][0]);
            acc[1][1] = fmaf(w1, sv.y, acc[1][1]);
            acc[1][2] = fmaf(w1, sv.z, acc[1][2]);
            acc[1][3] = fmaf(w1, sv.w, acc[1][3]);
            acc[2][0] = fmaf(w2, sv.x, acc[2][0]);
            acc[2][1] = fmaf(w2, sv.y, acc[2][1]);
            acc[2][2] = fmaf(w2, sv.z, acc[2][2]);
            acc[2][3] = fmaf(w2, sv.w, acc[2][3]);
            acc[3][0] = fmaf(w3, sv.x, acc[3][0]);
            acc[3][1] = fmaf(w3, sv.y, acc[3][1]);
            acc[3][2] = fmaf(w3, sv.z, acc[3][2]);
            acc[3][3] = fmaf(w3, sv.w, acc[3][3]);
        }
        const float H0 = (float)(1.0 / (4.0 * 1.2858 * 1.2858));
        #pragma unroll
        for (int r = 0; r < 4; ++r) {
            const float4 c = *(const float4*)&s4[pj][J0 + 92 * r][0];
            acc[r][0] = fmaf(H0, c.x, acc[r][0]);
            acc[r][1] = fmaf(H0, c.y, acc[r][1]);
            acc[r][2] = fmaf(H0, c.z, acc[r][2]);
            acc[r][3] = fmaf(H0, c.w, acc[r][3]);
        }
        #pragma unroll
        for (int r = 0; r < 4; ++r) {
            const int j = 2 * (J0 + 92 * r) + pj;
            #pragma unroll
            for (int vv = 0; vv < 4; ++vv)
                Q[(v0 + vv) * NU + j] = acc[r][vv] * 1.2858f;
        }
    }
}

// ---------------- Stage 3: backprojection ----------------------------------------------
// Block = one image row (ix uniform) x one view-quarter: 2048 blocks, 8 waves/SIMD.
// Thread: 2 adjacent pixels (jy=2t, 2t+1), 2 independent gather chains.
// NUMERICS: per-pixel arithmetic is kept BIT-IDENTICAL to the R3 kernel (passed twice):
//   t2 = fmaf(tv.x, X, tv.y*Y); D = fmaf(tv.w, X, fmaf(tv.z, -Y, 595)); rD = rcp(D);
//   fidx = fmaf(t2, rD, 367.5); gate |fidx-367.5| <= 367.5; i0 = med3(int(fidx),0,734).
// R4's reassociated variant flipped an edge-grazing (px,view) gate vs the reference
// (one-view quantum = ~1.4e-3 error). Do NOT reassociate these chains.
// Interior waves (both px r<=236.5mm => max|fidx-367.5| = 365.7 < 367.5 for ALL views)
// skip clamp+gate — provably bit-identical to the full path there.
__global__ __launch_bounds__(256) void bp_kernel(const float* __restrict__ Q,
                                                 const float4* __restrict__ trig,
                                                 float* __restrict__ out) {
    const int b = blockIdx.x;
    const int h = b & 3;                      // view quarter: [180h, 180h+180)
    const int ix = b >> 2;                    // image row (block-uniform)
    const int t = threadIdx.x;
    const float dx = 400.0f / 512.0f;         // 0.78125 exact
    const float X   = ((float)ix - 255.5f) * dx;         // uniform
    const float Ya  = ((float)(2 * t) - 255.5f) * dx;
    const float Yb  = Ya + dx;
    const float nYa = -Ya;
    const float nYb = -Yb;

    const float4* tvp = trig + h * 180;
    const float* Qb = Q + h * 180 * NU;

    float acca = 0.0f, accb = 0.0f;
    const float rmax2 = 236.5f * 236.5f;
    const bool inr = fmaxf(fmaf(X, X, Ya * Ya), fmaf(X, X, Yb * Yb)) <= rmax2;

    if (__all(inr)) {
        #pragma unroll 2
        for (int v = 0; v < 180; ++v) {
            const float4 tv = tvp[v];
            float t2a = fmaf(tv.x, X, tv.y * Ya);               // R3-exact
            float t2b = fmaf(tv.x, X, tv.y * Yb);
            float Da  = fmaf(tv.w, X, fmaf(tv.z, nYa, 595.0f)); // R3-exact
            float Db  = fmaf(tv.w, X, fmaf(tv.z, nYb, 595.0f));
            float rDa = __builtin_amdgcn_rcpf(Da);
            float rDb = __builtin_amdgcn_rcpf(Db);
            float fia = fmaf(t2a, rDa, 367.5f);
            float fib = fmaf(t2b, rDb, 367.5f);
            unsigned ia = (unsigned)(int)fia;                   // in [0,734] by geometry
            unsigned ib = (unsigned)(int)fib;
            float fa = __builtin_amdgcn_fractf(fia);
            float fb = __builtin_amdgcn_fractf(fib);
            const float* Qv = Qb + v * NU;
            float qa0 = Qv[ia], qa1 = Qv[ia + 1];
            float qb0 = Qv[ib], qb1 = Qv[ib + 1];
            float va = fmaf(fa, qa1 - qa0, qa0);
            float vb = fmaf(fb, qb1 - qb0, qb0);
            acca = fmaf(rDa * rDa, va, acca);
            accb = fmaf(rDb * rDb, vb, accb);
        }
    } else {
        #pragma unroll 2
        for (int v = 0; v < 180; ++v) {
            const float4 tv = tvp[v];
            float t2a = fmaf(tv.x, X, tv.y * Ya);
            float t2b = fmaf(tv.x, X, tv.y * Yb);
            float Da  = fmaf(tv.w, X, fmaf(tv.z, nYa, 595.0f));
            float Db  = fmaf(tv.w, X, fmaf(tv.z, nYb, 595.0f));
            float rDa = __builtin_amdgcn_rcpf(Da);
            float rDb = __builtin_amdgcn_rcpf(Db);
            float fia = fmaf(t2a, rDa, 367.5f);
            float fib = fmaf(t2b, rDb, 367.5f);
            int ia = min(max((int)fia, 0), NU - 2);             // v_med3_i32
            int ib = min(max((int)fib, 0), NU - 2);
            float fa = __builtin_amdgcn_fractf(fia);
            float fb = __builtin_amdgcn_fractf(fib);
            const float* Qv = Qb + v * NU;
            float qa0 = Qv[ia], qa1 = Qv[ia + 1];
            float qb0 = Qv[ib], qb1 = Qv[ib + 1];
            float va = fmaf(fa, qa1 - qa0, qa0);
            float vb = fmaf(fb, qb1 - qb0, qb0);
            float cena = fia - 367.5f;                          // R3-exact gate
            float cenb = fib - 367.5f;
            float ga = (__builtin_fabsf(cena) <= 367.5f) ? rDa * rDa : 0.0f;
            float gb = (__builtin_fabsf(cenb) <= 367.5f) ? rDb * rDb : 0.0f;
            acca = fmaf(ga, va, acca);
            accb = fmaf(gb, vb, accb);
        }
    }
    const float SC = (float)(595.0 * 595.0 * 0.5 * (2.0 * M_PI / 720.0));
    const int p0 = ix * NXY + 2 * t;
    unsafeAtomicAdd(&out[p0], acca * SC);
    unsafeAtomicAdd(&out[p0 + 1], accb * SC);
}

extern "C" void kernel_launch(void* const* d_in, const int* in_sizes, int n_in,
                              void* d_out, int out_size, void* d_ws, size_t ws_size,
                              hipStream_t stream) {
    const float* sino = (const float*)d_in[0];
    float* out = (float*)d_out;
    float* Q = (float*)d_ws;                                          // 720*736*4 = 2.12 MB
    float4* trig = (float4*)((char*)d_ws + NV * NU * sizeof(float));  // +11.5 KB (16B aligned)

    filter_kernel<<<NV / 4, 192, 0, stream>>>(sino, Q, trig);
    hipMemsetAsync(out, 0, (size_t)NXY * NXY * sizeof(float), stream);  // atomic targets
    bp_kernel<<<4 * NXY, 256, 0, stream>>>(Q, trig, out);
}

// Round 6
// 164.754 us; speedup vs baseline: 1.2362x; 1.2362x over previous
//
#include <hip/hip_runtime.h>
#include <math.h>

#define NV 720
#define NU 736
#define NXY 512

// ---------------- Stage 1+2: cosine weight + Ram-Lak Toeplitz GEMM (+ trig table) ------
__global__ __launch_bounds__(192) void filter_kernel(const float* __restrict__ sino,
                                                     float* __restrict__ Q,
                                                     float4* __restrict__ trig) {
    __shared__ float s4[2][368][4];   // [parity][m][view]
    __shared__ float wco[736];        // wco[i] = -1/(pi*(2i-735)*DU)^2
    const int v0 = blockIdx.x * 4;
    const int t = threadIdx.x;

    if (t < 4) {
        int v = v0 + t;
        float beta = (float)((double)v * (2.0 * M_PI / 720.0));
        float cb = cosf(beta), sb = sinf(beta);
        const float K = (float)(1085.6 / 1.2858);   // DSD/DU
        trig[v] = make_float4(cb * K, sb * K, cb, sb);
    }
    for (int i = t; i < 736; i += 192) {
        double n = (double)(2 * i - 735);
        double a = M_PI * n * 1.2858;
        wco[i] = (float)(-1.0 / (a * a));
    }
    const float DSD2 = (float)(1085.6 * 1085.6);
    for (int vv = 0; vv < 4; ++vv) {
        for (int u = t; u < 736; u += 192) {
            float us = ((float)u - 367.5f) * 1.2858f;
            float cw = 1085.6f / sqrtf(DSD2 + us * us);
            s4[u & 1][u >> 1][vv] = sino[(v0 + vv) * NU + u] * cw;
        }
    }
    __syncthreads();

    if (t < 184) {
        const int pj = (t < 92) ? 1 : 0;
        const int J0 = (t < 92) ? t : t - 92;
        const int q = 1 - pj;
        float acc[4][4];
        #pragma unroll
        for (int r = 0; r < 4; ++r)
            #pragma unroll
            for (int vv = 0; vv < 4; ++vv) acc[r][vv] = 0.0f;

        const int ibase0 = J0 + 367 + pj;
        #pragma unroll 4
        for (int m = 0; m < 368; ++m) {
            const float4 sv = *(const float4*)&s4[q][m][0];
            const int ib = ibase0 - m;
            const float w0 = wco[ib];
            const float w1 = wco[ib + 92];
            const float w2 = wco[ib + 184];
            const float w3 = wco[ib + 276];
            acc[0][0] = fmaf(w0, sv.x, acc[0][0]);
            acc[0][1] = fmaf(w0, sv.y, acc[0][1]);
            acc[0][2] = fmaf(w0, sv.z, acc[0][2]);
            acc[0][3] = fmaf(w0, sv.w, acc[0][3]);
            acc[1][0] = fmaf(w1, sv.x, acc[1][0]);
            acc[1][1] = fmaf(w1, sv.y, acc[1][1]);
            acc[1][2] = fmaf(w1, sv.z, acc[1][2]);
            acc[1][3] = fmaf(w1, sv.w, acc[1][3]);
            acc[2][0] = fmaf(w2, sv.x, acc[2][0]);
            acc[2][1] = fmaf(w2, sv.y, acc[2][1]);
            acc[2][2] = fmaf(w2, sv.z, acc[2][2]);
            acc[2][3] = fmaf(w2, sv.w, acc[2][3]);
            acc[3][0] = fmaf(w3, sv.x, acc[3][0]);
            acc[3][1] = fmaf(w3, sv.y, acc[3][1]);
            acc[3][2] = fmaf(w3, sv.z, acc[3][2]);
            acc[3][3] = fmaf(w3, sv.w, acc[3][3]);
        }
        const float H0 = (float)(1.0 / (4.0 * 1.2858 * 1.2858));
        #pragma unroll
        for (int r = 0; r < 4; ++r) {
            const float4 c = *(const float4*)&s4[pj][J0 + 92 * r][0];
            acc[r][0] = fmaf(H0, c.x, acc[r][0]);
            acc[r][1] = fmaf(H0, c.y, acc[r][1]);
            acc[r][2] = fmaf(H0, c.z, acc[r][2]);
            acc[r][3] = fmaf(H0, c.w, acc[r][3]);
        }
        #pragma unroll
        for (int r = 0; r < 4; ++r) {
            const int j = 2 * (J0 + 92 * r) + pj;
            #pragma unroll
            for (int vv = 0; vv < 4; ++vv)
                Q[(v0 + vv) * NU + j] = acc[r][vv] * 1.2858f;
        }
    }
}

// ---------------- Stage 3: backprojection (R3 structure + interior specialization) -----
// LESSON (R5): keep ONE pixel per lane — a wave's gather footprint (64 adjacent jy,
// ~70 detector bins, ~5 cache lines/load) is what keeps the L1 gather pipe cheap.
// 2px/lane doubled per-instruction address spread and stalled VALU to 50%.
// Structure = R3 exactly (2048 blocks: pixel-half x view-half, 1 px/lane, 8 waves/SIMD).
// Added: waves with all-lane r <= 236.5mm (~87%) skip clamp+gate — bit-identical there
// since max |fidx-367.5| = r*K/sqrt(DSO^2-r^2) = 365.7 < 367.5.
// NUMERICS: R3-exact chains; do NOT reassociate (R4 flipped an edge gate -> 1.4e-3).
__global__ __launch_bounds__(256) void bp_kernel(const float* __restrict__ Q,
                                                 const float4* __restrict__ trig,
                                                 float* __restrict__ out) {
    const int b = blockIdx.x;
    const int h = b & 1;                      // view half: [0,360) or [360,720)
    const int p = (b >> 1) * 256 + threadIdx.x;
    const int ix = p >> 9;
    const int jy = p & 511;
    const float dx = 400.0f / 512.0f;         // 0.78125 exact
    const float X  = ((float)ix - 255.5f) * dx;
    const float Y  = ((float)jy - 255.5f) * dx;
    const float nY = -Y;

    float acc = 0.0f;
    const float* qrow = Q + h * 360 * NU;
    const float4* tvp = trig + h * 360;
    const bool inr = fmaf(X, X, Y * Y) <= 236.5f * 236.5f;

    if (__all(inr)) {
        #pragma unroll 4
        for (int v = 0; v < 360; ++v) {
            const float4 tv = tvp[v];
            float t2 = fmaf(tv.x, X, tv.y * Y);                 // R3-exact
            float D  = fmaf(tv.w, X, fmaf(tv.z, nY, 595.0f));   // R3-exact
            float rD = __builtin_amdgcn_rcpf(D);
            float fidx = fmaf(t2, rD, 367.5f);
            unsigned i0 = (unsigned)(int)fidx;                  // in [0,734] by geometry
            float f = __builtin_amdgcn_fractf(fidx);
            float q0 = qrow[i0];
            float q1 = qrow[i0 + 1];
            float val = fmaf(f, q1 - q0, q0);
            acc = fmaf(rD * rD, val, acc);
            qrow += NU;
        }
    } else {
        #pragma unroll 4
        for (int v = 0; v < 360; ++v) {
            const float4 tv = tvp[v];
            float t2 = fmaf(tv.x, X, tv.y * Y);
            float D  = fmaf(tv.w, X, fmaf(tv.z, nY, 595.0f));
            float rD = __builtin_amdgcn_rcpf(D);
            float fidx = fmaf(t2, rD, 367.5f);
            int i0 = (int)fidx;
            int i0c = min(max(i0, 0), NU - 2);                  // v_med3_i32
            float f = __builtin_amdgcn_fractf(fidx);
            float q0 = qrow[i0c];
            float q1 = qrow[i0c + 1];
            float val = fmaf(f, q1 - q0, q0);
            float g = rD * rD;
            float cen = fidx - 367.5f;
            g = (__builtin_fabsf(cen) <= 367.5f) ? g : 0.0f;
            acc = fmaf(g, val, acc);
            qrow += NU;
        }
    }
    const float SC = (float)(595.0 * 595.0 * 0.5 * (2.0 * M_PI / 720.0));
    unsafeAtomicAdd(&out[p], acc * SC);
}

extern "C" void kernel_launch(void* const* d_in, const int* in_sizes, int n_in,
                              void* d_out, int out_size, void* d_ws, size_t ws_size,
                              hipStream_t stream) {
    const float* sino = (const float*)d_in[0];
    float* out = (float*)d_out;
    float* Q = (float*)d_ws;                                          // 720*736*4 = 2.12 MB
    float4* trig = (float4*)((char*)d_ws + NV * NU * sizeof(float));  // +11.5 KB (16B aligned)

    filter_kernel<<<NV / 4, 192, 0, stream>>>(sino, Q, trig);
    hipMemsetAsync(out, 0, (size_t)NXY * NXY * sizeof(float), stream);  // atomic targets
    bp_kernel<<<2 * (NXY * NXY) / 256, 256, 0, stream>>>(Q, trig, out);
}

// Round 7
// 162.711 us; speedup vs baseline: 1.2517x; 1.0126x over previous
//
#include <hip/hip_runtime.h>
#include <math.h>

#define NV 720
#define NU 736
#define NXY 512

// ---------------- Stage 1+2: cosine weight + Ram-Lak Toeplitz GEMM (+ trig table) ------
__global__ __launch_bounds__(192) void filter_kernel(const float* __restrict__ sino,
                                                     float* __restrict__ Q,
                                                     float4* __restrict__ trig) {
    __shared__ float s4[2][368][4];   // [parity][m][view]
    __shared__ float wco[736];        // wco[i] = -1/(pi*(2i-735)*DU)^2
    const int v0 = blockIdx.x * 4;
    const int t = threadIdx.x;

    if (t < 4) {
        int v = v0 + t;
        float beta = (float)((double)v * (2.0 * M_PI / 720.0));
        float cb = cosf(beta), sb = sinf(beta);
        const float K = (float)(1085.6 / 1.2858);   // DSD/DU
        trig[v] = make_float4(cb * K, sb * K, cb, sb);
    }
    for (int i = t; i < 736; i += 192) {
        double n = (double)(2 * i - 735);
        double a = M_PI * n * 1.2858;
        wco[i] = (float)(-1.0 / (a * a));
    }
    const float DSD2 = (float)(1085.6 * 1085.6);
    for (int vv = 0; vv < 4; ++vv) {
        for (int u = t; u < 736; u += 192) {
            float us = ((float)u - 367.5f) * 1.2858f;
            float cw = 1085.6f / sqrtf(DSD2 + us * us);
            s4[u & 1][u >> 1][vv] = sino[(v0 + vv) * NU + u] * cw;
        }
    }
    __syncthreads();

    if (t < 184) {
        const int pj = (t < 92) ? 1 : 0;
        const int J0 = (t < 92) ? t : t - 92;
        const int q = 1 - pj;
        float acc[4][4];
        #pragma unroll
        for (int r = 0; r < 4; ++r)
            #pragma unroll
            for (int vv = 0; vv < 4; ++vv) acc[r][vv] = 0.0f;

        const int ibase0 = J0 + 367 + pj;
        #pragma unroll 4
        for (int m = 0; m < 368; ++m) {
            const float4 sv = *(const float4*)&s4[q][m][0];
            const int ib = ibase0 - m;
            const float w0 = wco[ib];
            const float w1 = wco[ib + 92];
            const float w2 = wco[ib + 184];
            const float w3 = wco[ib + 276];
            acc[0][0] = fmaf(w0, sv.x, acc[0][0]);
            acc[0][1] = fmaf(w0, sv.y, acc[0][1]);
            acc[0][2] = fmaf(w0, sv.z, acc[0][2]);
            acc[0][3] = fmaf(w0, sv.w, acc[0][3]);
            acc[1][0] = fmaf(w1, sv.x, acc[1][0]);
            acc[1][1] = fmaf(w1, sv.y, acc[1][1]);
            acc[1][2] = fmaf(w1, sv.z, acc[1][2]);
            acc[1][3] = fmaf(w1, sv.w, acc[1][3]);
            acc[2][0] = fmaf(w2, sv.x, acc[2][0]);
            acc[2][1] = fmaf(w2, sv.y, acc[2][1]);
            acc[2][2] = fmaf(w2, sv.z, acc[2][2]);
            acc[2][3] = fmaf(w2, sv.w, acc[2][3]);
            acc[3][0] = fmaf(w3, sv.x, acc[3][0]);
            acc[3][1] = fmaf(w3, sv.y, acc[3][1]);
            acc[3][2] = fmaf(w3, sv.z, acc[3][2]);
            acc[3][3] = fmaf(w3, sv.w, acc[3][3]);
        }
        const float H0 = (float)(1.0 / (4.0 * 1.2858 * 1.2858));
        #pragma unroll
        for (int r = 0; r < 4; ++r) {
            const float4 c = *(const float4*)&s4[pj][J0 + 92 * r][0];
            acc[r][0] = fmaf(H0, c.x, acc[r][0]);
            acc[r][1] = fmaf(H0, c.y, acc[r][1]);
            acc[r][2] = fmaf(H0, c.z, acc[r][2]);
            acc[r][3] = fmaf(H0, c.w, acc[r][3]);
        }
        #pragma unroll
        for (int r = 0; r < 4; ++r) {
            const int j = 2 * (J0 + 92 * r) + pj;
            #pragma unroll
            for (int vv = 0; vv < 4; ++vv)
                Q[(v0 + vv) * NU + j] = acc[r][vv] * 1.2858f;
        }
    }
}

// ---------------- Stage 3: backprojection (R6 structure, fused float2 gather) ----------
// R6 finding: bp has a ~106us co-bottleneck on the L1/TA gather pipe (~11 cyc per
// divergent wave-load; VALU diet lowered busy% without lowering time). Fix: fuse the
// q0/q1 taps (adjacent addresses) into ONE global_load_dwordx2 — halves TA instruction
// count and line touches. gfx950 unaligned-access-mode makes 4B-aligned dwordx2 correct.
// Loaded values are bit-identical -> absmax must stay 3.051758e-04.
// NUMERICS: R3-exact chains; do NOT reassociate (R4 lesson). One pixel per lane (R5 lesson).
__global__ __launch_bounds__(256) void bp_kernel(const float* __restrict__ Q,
                                                 const float4* __restrict__ trig,
                                                 float* __restrict__ out) {
    const int b = blockIdx.x;
    const int h = b & 1;                      // view half: [0,360) or [360,720)
    const int p = (b >> 1) * 256 + threadIdx.x;
    const int ix = p >> 9;
    const int jy = p & 511;
    const float dx = 400.0f / 512.0f;         // 0.78125 exact
    const float X  = ((float)ix - 255.5f) * dx;
    const float Y  = ((float)jy - 255.5f) * dx;
    const float nY = -Y;

    float acc = 0.0f;
    const float* qrow = Q + h * 360 * NU;
    const float4* tvp = trig + h * 360;
    const bool inr = fmaf(X, X, Y * Y) <= 236.5f * 236.5f;

    if (__all(inr)) {
        #pragma unroll 4
        for (int v = 0; v < 360; ++v) {
            const float4 tv = tvp[v];
            float t2 = fmaf(tv.x, X, tv.y * Y);                 // R3-exact
            float D  = fmaf(tv.w, X, fmaf(tv.z, nY, 595.0f));   // R3-exact
            float rD = __builtin_amdgcn_rcpf(D);
            float fidx = fmaf(t2, rD, 367.5f);
            unsigned i0 = (unsigned)(int)fidx;                  // in [0,734] by geometry
            float f = __builtin_amdgcn_fractf(fidx);
            float2 qq = *(const float2*)(qrow + i0);            // global_load_dwordx2
            float val = fmaf(f, qq.y - qq.x, qq.x);
            acc = fmaf(rD * rD, val, acc);
            qrow += NU;
        }
    } else {
        #pragma unroll 4
        for (int v = 0; v < 360; ++v) {
            const float4 tv = tvp[v];
            float t2 = fmaf(tv.x, X, tv.y * Y);
            float D  = fmaf(tv.w, X, fmaf(tv.z, nY, 595.0f));
            float rD = __builtin_amdgcn_rcpf(D);
            float fidx = fmaf(t2, rD, 367.5f);
            int i0 = (int)fidx;
            int i0c = min(max(i0, 0), NU - 2);                  // v_med3_i32
            float f = __builtin_amdgcn_fractf(fidx);
            float2 qq = *(const float2*)(qrow + i0c);           // global_load_dwordx2
            float val = fmaf(f, qq.y - qq.x, qq.x);
            float g = rD * rD;
            float cen = fidx - 367.5f;
            g = (__builtin_fabsf(cen) <= 367.5f) ? g : 0.0f;
            acc = fmaf(g, val, acc);
            qrow += NU;
        }
    }
    const float SC = (float)(595.0 * 595.0 * 0.5 * (2.0 * M_PI / 720.0));
    unsafeAtomicAdd(&out[p], acc * SC);
}

extern "C" void kernel_launch(void* const* d_in, const int* in_sizes, int n_in,
                              void* d_out, int out_size, void* d_ws, size_t ws_size,
                              hipStream_t stream) {
    const float* sino = (const float*)d_in[0];
    float* out = (float*)d_out;
    float* Q = (float*)d_ws;                                          // 720*736*4 = 2.12 MB
    float4* trig = (float4*)((char*)d_ws + NV * NU * sizeof(float));  // +11.5 KB (16B aligned)

    filter_kernel<<<NV / 4, 192, 0, stream>>>(sino, Q, trig);
    hipMemsetAsync(out, 0, (size_t)NXY * NXY * sizeof(float), stream);  // atomic targets
    bp_kernel<<<2 * (NXY * NXY) / 256, 256, 0, stream>>>(Q, trig, out);
}